// Round 5
// baseline (1592.698 us; speedup 1.0000x reference)
//
#include <hip/hip_runtime.h>
#include <hip/hip_bf16.h>

#define B_    128
#define T_    200
#define C_    40
#define NCODE 2000
#define DAUX  16
#define E_    128
#define H_    256
#define G4    512          // 4*E

__device__ __forceinline__ float sigmoid_fast(float x) {
    return __fdividef(1.f, 1.f + __expf(-x));
}
__device__ __forceinline__ float tanh_fast(float x) {
    x = fminf(15.f, fmaxf(-15.f, x));
    float e = __expf(2.f * x);
    return __fdividef(e - 1.f, e + 1.f);
}

// ---------------------------------------------------------------------------
// Kernel 1: front-end. multi-hot (set semantics, drop code 0) @ W_lin + aux
// part + bias, ReLU. One workgroup per (b,t) cell, 128 threads (one per E dim).
// Dead cells (t >= length[b]) write zeros and exit.
// ---------------------------------------------------------------------------
__global__ __launch_bounds__(128) void fe_kernel(
    const int* __restrict__ code, const float* __restrict__ aux,
    const float* __restrict__ W_lin, const float* __restrict__ b_lin,
    const int* __restrict__ length, float* __restrict__ x)
{
    const int cell = blockIdx.x;          // b*T_ + t
    const int e = threadIdx.x;            // 0..127
    const int b = cell / T_;
    const int t = cell - b * T_;

    if (t >= length[b]) {                 // dead cell: zero-fill (uniform exit)
        x[(size_t)cell * E_ + e] = 0.f;
        return;
    }

    __shared__ int codes[C_];
    __shared__ int keep[C_];

    if (e < C_) codes[e] = code[cell * C_ + e];
    __syncthreads();
    if (e < C_) {
        int cj = codes[e];
        int k = (cj != 0);                // code 0 = padding column, dropped
        for (int i = 0; i < e; ++i)       // set-semantics: keep first occurrence
            if (codes[i] == cj) k = 0;
        keep[e] = k;
    }
    __syncthreads();

    float acc = b_lin[e];
    #pragma unroll 8
    for (int j = 0; j < C_; ++j) {
        int cj = codes[j];
        float w = (float)keep[j];
        int row = (cj > 0) ? (cj - 1) : 0;     // safe row even when skipped
        acc = fmaf(w, W_lin[row * E_ + e], acc);
    }
    const float* arow = aux + (size_t)cell * DAUX;
    #pragma unroll
    for (int d = 0; d < DAUX; ++d)
        acc = fmaf(arow[d], W_lin[(NCODE + d) * E_ + e], acc);

    x[(size_t)cell * E_ + e] = fmaxf(acc, 0.f);
}

// ---------------------------------------------------------------------------
// Kernel 2: z_pre = x @ W_x + b_lstm.   [25600,128] @ [128,512]
// 64x64 tiles, XOR-swizzled LDS, 4x4 micro-tile per thread.
// Tiles whose 64 rows are all dead (t >= len within one batch row) exit early.
// ---------------------------------------------------------------------------
__global__ __launch_bounds__(256) void gemm_kernel(
    const float* __restrict__ x, const float* __restrict__ Wx,
    const float* __restrict__ bl, const int* __restrict__ length,
    float* __restrict__ z)
{
    const int m0 = blockIdx.x * 64;
    const int n0 = blockIdx.y * 64;

    // dead-tile check (uniform): tile spans rows m0..m0+63
    {
        int b_first = m0 / T_;
        int b_last  = (m0 + 63) / T_;
        if (b_first == b_last && (m0 - b_first * T_) >= length[b_first])
            return;                        // whole tile beyond this row's length
    }

    __shared__ float4 As[64][32];   // [row][k4], col swizzled by (row&7)
    __shared__ float4 Bt[64][32];   // [col][k4], col swizzled by (col&7)

    const int tid = threadIdx.x;

    const float4* x4 = (const float4*)x;
    #pragma unroll
    for (int i = 0; i < 8; ++i) {
        int idx = tid + i * 256;              // 0..2047
        int r = idx >> 5, c = idx & 31;
        As[r][c ^ (r & 7)] = x4[(size_t)(m0 + r) * 32 + c];
    }
    #pragma unroll
    for (int i = 0; i < 32; ++i) {
        int idx = tid + i * 256;              // 0..8191
        int k = idx >> 6, n = idx & 63;       // consecutive n -> coalesced
        ((float*)&Bt[n][(k >> 2) ^ (n & 7)])[k & 3] = Wx[k * G4 + n0 + n];
    }
    __syncthreads();

    const int tn = tid & 15;                  // col group
    const int tm = tid >> 4;                  // row group 0..15
    float acc[4][4] = {};

    #pragma unroll
    for (int k4 = 0; k4 < 32; ++k4) {
        float4 a[4], bb[4];
        #pragma unroll
        for (int i = 0; i < 4; ++i) {
            int r = 4 * tm + i;
            a[i] = As[r][k4 ^ (r & 7)];
        }
        #pragma unroll
        for (int c = 0; c < 4; ++c)
            bb[c] = Bt[tn + 16 * c][k4 ^ (tn & 7)];
        #pragma unroll
        for (int i = 0; i < 4; ++i)
            #pragma unroll
            for (int c = 0; c < 4; ++c) {
                acc[i][c] = fmaf(a[i].x, bb[c].x, acc[i][c]);
                acc[i][c] = fmaf(a[i].y, bb[c].y, acc[i][c]);
                acc[i][c] = fmaf(a[i].z, bb[c].z, acc[i][c]);
                acc[i][c] = fmaf(a[i].w, bb[c].w, acc[i][c]);
            }
    }

    #pragma unroll
    for (int i = 0; i < 4; ++i) {
        int row = m0 + 4 * tm + i;
        #pragma unroll
        for (int c = 0; c < 4; ++c) {
            int col = n0 + tn + 16 * c;
            z[(size_t)row * G4 + col] = acc[i][c] + bl[col];
        }
    }
}

// ---------------------------------------------------------------------------
// Kernel 3: LSTM. One workgroup per batch row. 512 threads: thread
// (j = tid>>2, ks = tid&3) owns gate-column j for ALL FOUR gates over k-range
// [32ks, 32ks+32). Weight slices (128 floats/thread) MUST stay in VGPRs:
// __launch_bounds__(512, 2) raises the budget to 256 VGPRs/wave (R4's build
// at default occupancy allocated only 84 VGPRs and re-read 256 KB of weights
// from L2 every step — that WAS the bottleneck, ~190 µs of pure L2 traffic).
// h reads are issued in per-ks rotated chunk order so the 4 k-quarters hit
// banks {0,8,16,24}+q instead of colliding 4-way (R4: 3.2M conflicts).
// Register placement hreg[4*qq] keeps accumulation order bit-identical.
// ---------------------------------------------------------------------------
__global__ __launch_bounds__(512, 2) void lstm_kernel(
    const float* __restrict__ z_pre, const float* __restrict__ Wh,
    const int* __restrict__ length, float* __restrict__ last_h)
{
    const int b  = blockIdx.x;
    const int tid = threadIdx.x;
    const int j  = tid >> 2;     // 0..127 gate column
    const int ks = tid & 3;      // k-quarter

    __shared__ float h_lds[2][E_];

    // per-thread weight slice: w[g][kk] = Wh[(32ks+kk)][g*128 + j]  (128 VGPRs)
    float w0[32], w1[32], w2[32], w3[32];
    #pragma unroll
    for (int kk = 0; kk < 32; ++kk) {
        const float* row = Wh + (size_t)(32 * ks + kk) * G4 + j;
        w0[kk] = row[0];
        w1[kk] = row[E_];
        w2[kk] = row[2 * E_];
        w3[kk] = row[3 * E_];
    }

    const int len = length[b];
    const float* zp = z_pre + (size_t)b * T_ * G4;

    if (tid < E_) h_lds[0][tid] = 0.f;
    float c_reg = 0.f;
    // prefetch z for t=0 (z_pre already contains b_lstm)
    float z0 = zp[j], z1 = zp[E_ + j], z2 = zp[2 * E_ + j], z3 = zp[3 * E_ + j];
    __syncthreads();

    for (int s = 0; s < len; ++s) {
        const int cur = s & 1, nxt = cur ^ 1;

        // prefetch next step's z (hidden under this step's FMAs)
        const int tn = (s + 1 < len) ? s + 1 : s;
        const float* zn = zp + (size_t)tn * G4;
        float p0 = zn[j], p1 = zn[E_ + j], p2 = zn[2 * E_ + j], p3 = zn[3 * E_ + j];

        // h chunk for this k-quarter; per-ks rotated issue order -> the 4
        // quarters hit disjoint bank groups on every ds_read_b128.
        float hreg[32];
        #pragma unroll
        for (int q = 0; q < 8; ++q) {
            int qq = (q + 2 * ks) & 7;
            *(float4*)&hreg[4 * qq] =
                *(const float4*)&h_lds[cur][32 * ks + 4 * qq];
        }

        // recurrent partials from ZERO (z added once, after the reduction)
        float a0 = 0.f, a1 = 0.f, a2 = 0.f, a3 = 0.f;
        #pragma unroll
        for (int kk = 0; kk < 32; ++kk) {
            float h = hreg[kk];
            a0 = fmaf(h, w0[kk], a0);
            a1 = fmaf(h, w1[kk], a1);
            a2 = fmaf(h, w2[kk], a2);
            a3 = fmaf(h, w3[kk], a3);
        }
        // complete dot products across the 4 k-quarters (quad-local butterfly)
        a0 += __shfl_xor(a0, 1); a0 += __shfl_xor(a0, 2);
        a1 += __shfl_xor(a1, 1); a1 += __shfl_xor(a1, 2);
        a2 += __shfl_xor(a2, 1); a2 += __shfl_xor(a2, 2);
        a3 += __shfl_xor(a3, 1); a3 += __shfl_xor(a3, 2);
        a0 += z0; a1 += z1; a2 += z2; a3 += z3;

        // gates: i=a0, f=a1, g=a2, o=a3 (keras order)
        float ig = sigmoid_fast(a0);
        float fg = sigmoid_fast(a1);
        float gg = tanh_fast(a2);
        float og = sigmoid_fast(a3);
        c_reg = fg * c_reg + ig * gg;
        float h = og * tanh_fast(c_reg);

        if (ks == 0) {
            h_lds[nxt][j] = h;
            if (s == len - 1) last_h[b * E_ + j] = h;
        }
        z0 = p0; z1 = p1; z2 = p2; z3 = p3;
        __syncthreads();    // h[nxt] visible; everyone done with h[cur]
    }
}

// ---------------------------------------------------------------------------
// Kernel 4: MLP head + L2 normalize. One workgroup per batch row, 256 threads.
// ---------------------------------------------------------------------------
__global__ __launch_bounds__(256) void mlp_kernel(
    const float* __restrict__ last_h, const float* __restrict__ W0,
    const float* __restrict__ b0, const float* __restrict__ W1,
    const float* __restrict__ b1, float* __restrict__ out)
{
    const int b = blockIdx.x;
    const int j = threadIdx.x;    // 0..255

    __shared__ float lrow[E_];
    __shared__ float hid[H_];
    __shared__ float red[H_];

    if (j < E_) lrow[j] = last_h[b * E_ + j];
    __syncthreads();

    float a = b0[j];
    #pragma unroll 8
    for (int k = 0; k < E_; ++k)
        a = fmaf(lrow[k], W0[k * H_ + j], a);
    hid[j] = fmaxf(a, 0.f);
    __syncthreads();

    float f = b1[j];
    #pragma unroll 8
    for (int k = 0; k < H_; ++k)
        f = fmaf(hid[k], W1[k * H_ + j], f);

    red[j] = f * f;
    __syncthreads();
    #pragma unroll
    for (int s = 128; s > 0; s >>= 1) {
        if (j < s) red[j] += red[j + s];
        __syncthreads();
    }
    out[(size_t)b * H_ + j] = f / sqrtf(red[0]);
}

// ---------------------------------------------------------------------------
extern "C" void kernel_launch(void* const* d_in, const int* in_sizes, int n_in,
                              void* d_out, int out_size, void* d_ws, size_t ws_size,
                              hipStream_t stream)
{
    const int*   code  = (const int*)  d_in[0];
    const float* aux   = (const float*)d_in[1];
    const int*   length= (const int*)  d_in[2];
    // d_in[3] = is_training (ignored; inference path)
    const float* W_lin = (const float*)d_in[4];
    const float* b_lin = (const float*)d_in[5];
    const float* W_x   = (const float*)d_in[6];
    const float* W_h   = (const float*)d_in[7];
    const float* b_lstm= (const float*)d_in[8];
    const float* W0    = (const float*)d_in[9];
    const float* b0    = (const float*)d_in[10];
    const float* W1    = (const float*)d_in[11];
    const float* b1    = (const float*)d_in[12];
    float* out = (float*)d_out;

    // workspace layout
    char* ws = (char*)d_ws;
    float* x      = (float*)ws;                                   // 25600*128
    float* z_pre  = (float*)(ws + (size_t)B_ * T_ * E_ * 4);      // 25600*512
    float* last_h = (float*)(ws + (size_t)B_ * T_ * E_ * 4
                                + (size_t)B_ * T_ * G4 * 4);      // 128*128

    fe_kernel<<<B_ * T_, 128, 0, stream>>>(code, aux, W_lin, b_lin, length, x);
    gemm_kernel<<<dim3((B_ * T_) / 64, G4 / 64), 256, 0, stream>>>(x, W_x, b_lstm, length, z_pre);
    lstm_kernel<<<B_, 512, 0, stream>>>(z_pre, W_h, length, last_h);
    mlp_kernel<<<B_, H_, 0, stream>>>(last_h, W0, b0, W1, b1, out);
}

// Round 6
// 338.763 us; speedup vs baseline: 4.7015x; 4.7015x over previous
//
#include <hip/hip_runtime.h>
#include <hip/hip_bf16.h>

#define B_    128
#define T_    200
#define C_    40
#define NCODE 2000
#define DAUX  16
#define E_    128
#define H_    256
#define G4    512          // 4*E
#define HCH   36           // padded LDS chunk stride (32 + 4) -> conflict-free

__device__ __forceinline__ float sigmoid_fast(float x) {
    return __fdividef(1.f, 1.f + __expf(-x));
}
__device__ __forceinline__ float tanh_fast(float x) {
    x = fminf(15.f, fmaxf(-15.f, x));
    float e = __expf(2.f * x);
    return __fdividef(e - 1.f, e + 1.f);
}

// ---------------------------------------------------------------------------
// Kernel 1: front-end. multi-hot (set semantics, drop code 0) @ W_lin + aux
// part + bias, ReLU. One workgroup per (b,t) cell, 128 threads (one per E dim).
// Dead cells (t >= length[b]) write zeros and exit.
// ---------------------------------------------------------------------------
__global__ __launch_bounds__(128) void fe_kernel(
    const int* __restrict__ code, const float* __restrict__ aux,
    const float* __restrict__ W_lin, const float* __restrict__ b_lin,
    const int* __restrict__ length, float* __restrict__ x)
{
    const int cell = blockIdx.x;          // b*T_ + t
    const int e = threadIdx.x;            // 0..127
    const int b = cell / T_;
    const int t = cell - b * T_;

    if (t >= length[b]) {                 // dead cell: zero-fill (uniform exit)
        x[(size_t)cell * E_ + e] = 0.f;
        return;
    }

    __shared__ int codes[C_];
    __shared__ int keep[C_];

    if (e < C_) codes[e] = code[cell * C_ + e];
    __syncthreads();
    if (e < C_) {
        int cj = codes[e];
        int k = (cj != 0);                // code 0 = padding column, dropped
        for (int i = 0; i < e; ++i)       // set-semantics: keep first occurrence
            if (codes[i] == cj) k = 0;
        keep[e] = k;
    }
    __syncthreads();

    float acc = b_lin[e];
    #pragma unroll 8
    for (int j = 0; j < C_; ++j) {
        int cj = codes[j];
        float w = (float)keep[j];
        int row = (cj > 0) ? (cj - 1) : 0;     // safe row even when skipped
        acc = fmaf(w, W_lin[row * E_ + e], acc);
    }
    const float* arow = aux + (size_t)cell * DAUX;
    #pragma unroll
    for (int d = 0; d < DAUX; ++d)
        acc = fmaf(arow[d], W_lin[(NCODE + d) * E_ + e], acc);

    x[(size_t)cell * E_ + e] = fmaxf(acc, 0.f);
}

// ---------------------------------------------------------------------------
// Kernel 2: z_pre = x @ W_x + b_lstm.   [25600,128] @ [128,512]
// 64x64 tiles, XOR-swizzled LDS, 4x4 micro-tile per thread.
// Tiles whose 64 rows are all dead (t >= len within one batch row) exit early.
// ---------------------------------------------------------------------------
__global__ __launch_bounds__(256) void gemm_kernel(
    const float* __restrict__ x, const float* __restrict__ Wx,
    const float* __restrict__ bl, const int* __restrict__ length,
    float* __restrict__ z)
{
    const int m0 = blockIdx.x * 64;
    const int n0 = blockIdx.y * 64;

    // dead-tile check (uniform): tile spans rows m0..m0+63
    {
        int b_first = m0 / T_;
        int b_last  = (m0 + 63) / T_;
        if (b_first == b_last && (m0 - b_first * T_) >= length[b_first])
            return;                        // whole tile beyond this row's length
    }

    __shared__ float4 As[64][32];   // [row][k4], col swizzled by (row&7)
    __shared__ float4 Bt[64][32];   // [col][k4], col swizzled by (col&7)

    const int tid = threadIdx.x;

    const float4* x4 = (const float4*)x;
    #pragma unroll
    for (int i = 0; i < 8; ++i) {
        int idx = tid + i * 256;              // 0..2047
        int r = idx >> 5, c = idx & 31;
        As[r][c ^ (r & 7)] = x4[(size_t)(m0 + r) * 32 + c];
    }
    #pragma unroll
    for (int i = 0; i < 32; ++i) {
        int idx = tid + i * 256;              // 0..8191
        int k = idx >> 6, n = idx & 63;       // consecutive n -> coalesced
        ((float*)&Bt[n][(k >> 2) ^ (n & 7)])[k & 3] = Wx[k * G4 + n0 + n];
    }
    __syncthreads();

    const int tn = tid & 15;                  // col group
    const int tm = tid >> 4;                  // row group 0..15
    float acc[4][4] = {};

    #pragma unroll
    for (int k4 = 0; k4 < 32; ++k4) {
        float4 a[4], bb[4];
        #pragma unroll
        for (int i = 0; i < 4; ++i) {
            int r = 4 * tm + i;
            a[i] = As[r][k4 ^ (r & 7)];
        }
        #pragma unroll
        for (int c = 0; c < 4; ++c)
            bb[c] = Bt[tn + 16 * c][k4 ^ (tn & 7)];
        #pragma unroll
        for (int i = 0; i < 4; ++i)
            #pragma unroll
            for (int c = 0; c < 4; ++c) {
                acc[i][c] = fmaf(a[i].x, bb[c].x, acc[i][c]);
                acc[i][c] = fmaf(a[i].y, bb[c].y, acc[i][c]);
                acc[i][c] = fmaf(a[i].z, bb[c].z, acc[i][c]);
                acc[i][c] = fmaf(a[i].w, bb[c].w, acc[i][c]);
            }
    }

    #pragma unroll
    for (int i = 0; i < 4; ++i) {
        int row = m0 + 4 * tm + i;
        #pragma unroll
        for (int c = 0; c < 4; ++c) {
            int col = n0 + tn + 16 * c;
            z[(size_t)row * G4 + col] = acc[i][c] + bl[col];
        }
    }
}

// ---------------------------------------------------------------------------
// Kernel 3: LSTM. One workgroup per batch row. 512 threads: thread
// (j = tid>>2, ks = tid&3) owns gate-column j for all 4 gates over k-range
// [32ks, 32ks+32).
//   * __launch_bounds__(512, 2): 256-VGPR budget so the 128 weight floats are
//     hoisted out of the step loop (R4 at VGPR=84 re-read 256 KB/step from L2
//     -> 0.93 us/step, the measured bottleneck).
//   * ALL register indices are compile-time constants (R5's runtime-rotated
//     hreg index forced the array to scratch: WRITE_SIZE 64KB->8.2MB, 8x
//     slower — rule: runtime-indexed arrays go to local memory).
//   * Bank conflicts fixed by LAYOUT, not issue order: h element k lives at
//     LDS float 36*(k>>5) + (k&31). Quarter bases mod 32 = {0,4,8,12}, so at
//     read-slot q the 4 quarters hit disjoint bank groups. Pads never read.
// ---------------------------------------------------------------------------
__global__ __launch_bounds__(512, 2) void lstm_kernel(
    const float* __restrict__ z_pre, const float* __restrict__ Wh,
    const int* __restrict__ length, float* __restrict__ last_h)
{
    const int b  = blockIdx.x;
    const int tid = threadIdx.x;
    const int j  = tid >> 2;     // 0..127 gate column
    const int ks = tid & 3;      // k-quarter

    __shared__ float h_lds[2][4 * HCH];

    // per-thread weight slice: w[g][kk] = Wh[(32ks+kk)][g*128 + j]  (128 VGPRs)
    float w0[32], w1[32], w2[32], w3[32];
    #pragma unroll
    for (int kk = 0; kk < 32; ++kk) {
        const float* row = Wh + (size_t)(32 * ks + kk) * G4 + j;
        w0[kk] = row[0];
        w1[kk] = row[E_];
        w2[kk] = row[2 * E_];
        w3[kk] = row[3 * E_];
    }

    const int len = length[b];
    const float* zp = z_pre + (size_t)b * T_ * G4;

    if (tid < E_) h_lds[0][HCH * (tid >> 5) + (tid & 31)] = 0.f;
    float c_reg = 0.f;
    // prefetch z for t=0 (z_pre already contains b_lstm)
    float z0 = zp[j], z1 = zp[E_ + j], z2 = zp[2 * E_ + j], z3 = zp[3 * E_ + j];
    __syncthreads();

    for (int s = 0; s < len; ++s) {
        const int cur = s & 1, nxt = cur ^ 1;

        // prefetch next step's z (hidden under this step's FMAs)
        const int tn = (s + 1 < len) ? s + 1 : s;
        const float* zn = zp + (size_t)tn * G4;
        float p0 = zn[j], p1 = zn[E_ + j], p2 = zn[2 * E_ + j], p3 = zn[3 * E_ + j];

        // h chunk for this k-quarter (padded layout -> conflict-free float4s;
        // register indices 4q are static)
        float hreg[32];
        #pragma unroll
        for (int q = 0; q < 8; ++q)
            *(float4*)&hreg[4 * q] =
                *(const float4*)&h_lds[cur][HCH * ks + 4 * q];

        // recurrent partials from ZERO (z added once, after the reduction)
        float a0 = 0.f, a1 = 0.f, a2 = 0.f, a3 = 0.f;
        #pragma unroll
        for (int kk = 0; kk < 32; ++kk) {
            float h = hreg[kk];
            a0 = fmaf(h, w0[kk], a0);
            a1 = fmaf(h, w1[kk], a1);
            a2 = fmaf(h, w2[kk], a2);
            a3 = fmaf(h, w3[kk], a3);
        }
        // complete dot products across the 4 k-quarters (quad-local butterfly)
        a0 += __shfl_xor(a0, 1); a0 += __shfl_xor(a0, 2);
        a1 += __shfl_xor(a1, 1); a1 += __shfl_xor(a1, 2);
        a2 += __shfl_xor(a2, 1); a2 += __shfl_xor(a2, 2);
        a3 += __shfl_xor(a3, 1); a3 += __shfl_xor(a3, 2);
        a0 += z0; a1 += z1; a2 += z2; a3 += z3;

        // gates: i=a0, f=a1, g=a2, o=a3 (keras order)
        float ig = sigmoid_fast(a0);
        float fg = sigmoid_fast(a1);
        float gg = tanh_fast(a2);
        float og = sigmoid_fast(a3);
        c_reg = fg * c_reg + ig * gg;
        float h = og * tanh_fast(c_reg);

        if (ks == 0) {
            h_lds[nxt][HCH * (j >> 5) + (j & 31)] = h;
            if (s == len - 1) last_h[b * E_ + j] = h;
        }
        z0 = p0; z1 = p1; z2 = p2; z3 = p3;
        __syncthreads();    // h[nxt] visible; everyone done with h[cur]
    }
}

// ---------------------------------------------------------------------------
// Kernel 4: MLP head + L2 normalize. One workgroup per batch row, 256 threads.
// ---------------------------------------------------------------------------
__global__ __launch_bounds__(256) void mlp_kernel(
    const float* __restrict__ last_h, const float* __restrict__ W0,
    const float* __restrict__ b0, const float* __restrict__ W1,
    const float* __restrict__ b1, float* __restrict__ out)
{
    const int b = blockIdx.x;
    const int j = threadIdx.x;    // 0..255

    __shared__ float lrow[E_];
    __shared__ float hid[H_];
    __shared__ float red[H_];

    if (j < E_) lrow[j] = last_h[b * E_ + j];
    __syncthreads();

    float a = b0[j];
    #pragma unroll 8
    for (int k = 0; k < E_; ++k)
        a = fmaf(lrow[k], W0[k * H_ + j], a);
    hid[j] = fmaxf(a, 0.f);
    __syncthreads();

    float f = b1[j];
    #pragma unroll 8
    for (int k = 0; k < H_; ++k)
        f = fmaf(hid[k], W1[k * H_ + j], f);

    red[j] = f * f;
    __syncthreads();
    #pragma unroll
    for (int s = 128; s > 0; s >>= 1) {
        if (j < s) red[j] += red[j + s];
        __syncthreads();
    }
    out[(size_t)b * H_ + j] = f / sqrtf(red[0]);
}

// ---------------------------------------------------------------------------
extern "C" void kernel_launch(void* const* d_in, const int* in_sizes, int n_in,
                              void* d_out, int out_size, void* d_ws, size_t ws_size,
                              hipStream_t stream)
{
    const int*   code  = (const int*)  d_in[0];
    const float* aux   = (const float*)d_in[1];
    const int*   length= (const int*)  d_in[2];
    // d_in[3] = is_training (ignored; inference path)
    const float* W_lin = (const float*)d_in[4];
    const float* b_lin = (const float*)d_in[5];
    const float* W_x   = (const float*)d_in[6];
    const float* W_h   = (const float*)d_in[7];
    const float* b_lstm= (const float*)d_in[8];
    const float* W0    = (const float*)d_in[9];
    const float* b0    = (const float*)d_in[10];
    const float* W1    = (const float*)d_in[11];
    const float* b1    = (const float*)d_in[12];
    float* out = (float*)d_out;

    // workspace layout
    char* ws = (char*)d_ws;
    float* x      = (float*)ws;                                   // 25600*128
    float* z_pre  = (float*)(ws + (size_t)B_ * T_ * E_ * 4);      // 25600*512
    float* last_h = (float*)(ws + (size_t)B_ * T_ * E_ * 4
                                + (size_t)B_ * T_ * G4 * 4);      // 128*128

    fe_kernel<<<B_ * T_, 128, 0, stream>>>(code, aux, W_lin, b_lin, length, x);
    gemm_kernel<<<dim3((B_ * T_) / 64, G4 / 64), 256, 0, stream>>>(x, W_x, b_lstm, length, z_pre);
    lstm_kernel<<<B_, 512, 0, stream>>>(z_pre, W_h, length, last_h);
    mlp_kernel<<<B_, H_, 0, stream>>>(last_h, W0, b0, W1, b1, out);
}